// Round 1
// baseline (1081.397 us; speedup 1.0000x reference)
//
#include <hip/hip_runtime.h>
#include <hip/hip_bf16.h>
#include <stdint.h>

#define BB 64
#define SS 2048
#define TT 128
#define BDIM 256

// ---- bool-layout detection: mask[0,0] is always true (len >= 1024) ----
// mode 0: int32, 1: uint8, 2: float32, 3: bf16/u16
__device__ __forceinline__ int detect_mode(const void* maskp) {
    uint32_t w0 = ((const uint32_t*)maskp)[0];
    if (w0 == 1u) return 0;
    if (w0 == 0x3F800000u) return 2;
    if (w0 == 0x3F803F80u) return 3;
    return 1; // 0x01010101 (uint8) or anything else
}

__device__ __forceinline__ int mask_at(const void* maskp, int mode, size_t idx) {
    if (mode == 0) return ((const int*)maskp)[idx] != 0;
    if (mode == 1) return ((const unsigned char*)maskp)[idx] != 0;
    if (mode == 2) return ((const float*)maskp)[idx] != 0.f;
    return ((const unsigned short*)maskp)[idx] != 0;
}

// ---- Kernel 1: E[i][j] = forbidden ? 0 : exp(trans[i][j]) ----
__global__ void e_kernel(const void* __restrict__ forb, const float* __restrict__ trans,
                         const void* __restrict__ maskp, float* __restrict__ E) {
    int idx = blockIdx.x * BDIM + threadIdx.x;
    if (idx >= TT * TT) return;
    int mode = detect_mode(maskp);
    int fb = mask_at(forb, mode, idx);
    E[idx] = fb ? 0.0f : __expf(trans[idx]);
}

// ---- Kernel 2: forward scan (partition function z per batch) ----
__global__ __launch_bounds__(BDIM, 1) void fwd_kernel(
    const float* __restrict__ em, const void* __restrict__ maskp,
    const float* __restrict__ startt, const float* __restrict__ endt,
    const float* __restrict__ E, double* __restrict__ zout)
{
    const int b = blockIdx.x;
    const int t = threadIdx.x;
    const int j = t & 127;       // tag column this thread owns
    const int ig = t >> 7;       // which half of i (0: i=0..63, 1: i=64..127)
    const int lane = t & 63;
    const int wid = t >> 6;

    __shared__ __align__(16) float u[TT];   // exp-domain alpha (normalized)
    __shared__ float part[TT];              // ig==1 partial sums
    __shared__ float red[4];
    __shared__ int redi[4];

    const int mode = detect_mode(maskp);

    // ---- length of this batch (mask is a contiguous prefix) ----
    int cnt = 0;
    for (int s = t; s < SS; s += BDIM) cnt += mask_at(maskp, mode, (size_t)b * SS + s);
    #pragma unroll
    for (int off = 32; off >= 1; off >>= 1) cnt += __shfl_xor(cnt, off);
    if (lane == 0) redi[wid] = cnt;
    __syncthreads();
    const int len = redi[0] + redi[1] + redi[2] + redi[3];

    // ---- load this thread's 64-entry slice of E into registers ----
    float Ereg[64];
    {
        const float* Eb = E + (size_t)(ig * 64) * TT + j;
        #pragma unroll
        for (int i = 0; i < 64; ++i) Ereg[i] = Eb[(size_t)i * TT];
    }

    const float* emB = em + (size_t)b * SS * TT;
    double Cd = 0.0;

    // ---- init: alpha0 = start + em[:,0,:] -> exp domain ----
    {
        float a0 = startt[j] + emB[j];
        float m = a0;
        #pragma unroll
        for (int off = 32; off >= 1; off >>= 1) m = fmaxf(m, __shfl_xor(m, off));
        if (lane == 0) red[wid] = m;
        __syncthreads();
        float M = fmaxf(red[0], red[1]);
        if (ig == 0) u[j] = __expf(a0 - M);
        Cd = (double)M;
        __syncthreads();
    }

    // ---- main scan, groups of 4 steps, renorm once per group ----
    int k = 1;
    float emc[4], emn[4];
    if (ig == 0) {
        #pragma unroll
        for (int g = 0; g < 4; ++g) {
            int kk = k + g; kk = kk < SS ? kk : SS - 1;
            emc[g] = emB[(size_t)kk * TT + j];
        }
    }

    while (k + 4 <= len) {
        // prefetch next group's emissions (hidden under ~4 steps of compute)
        if (ig == 0) {
            #pragma unroll
            for (int g = 0; g < 4; ++g) {
                int kk = k + 4 + g; kk = kk < SS ? kk : SS - 1;
                emn[g] = emB[(size_t)kk * TT + j];
            }
        }
        #pragma unroll
        for (int g = 0; g < 4; ++g) {
            // matvec: p = sum over this thread's i-half of u[i]*E[i][j]
            float p = 0.f;
            const float4* u4 = (const float4*)(u + ig * 64);
            #pragma unroll
            for (int ii = 0; ii < 16; ++ii) {
                float4 uv = u4[ii];
                p = fmaf(uv.x, Ereg[4 * ii + 0], p);
                p = fmaf(uv.y, Ereg[4 * ii + 1], p);
                p = fmaf(uv.z, Ereg[4 * ii + 2], p);
                p = fmaf(uv.w, Ereg[4 * ii + 3], p);
            }
            if (ig == 1) part[j] = p;
            __syncthreads();
            float vnew = 0.f;
            if (ig == 0) vnew = (p + part[j]) * __expf(emc[g]);
            if (g == 3) {
                // renorm: u <- v / max(v); C += log(max)
                float m = (ig == 0) ? vnew : 0.f;
                #pragma unroll
                for (int off = 32; off >= 1; off >>= 1) m = fmaxf(m, __shfl_xor(m, off));
                if (lane == 0) red[wid] = m;
                __syncthreads();
                float M = fmaxf(red[0], red[1]);
                if (ig == 0) u[j] = vnew / M;
                Cd += (double)__logf(M);
                __syncthreads();
            } else {
                if (ig == 0) u[j] = vnew;
                __syncthreads();
            }
        }
        if (ig == 0) {
            #pragma unroll
            for (int g = 0; g < 4; ++g) emc[g] = emn[g];
        }
        k += 4;
    }

    // ---- tail steps (<=3), renorm every step ----
    while (k < len) {
        float emv = 0.f;
        if (ig == 0) emv = emB[(size_t)k * TT + j];
        float p = 0.f;
        const float4* u4 = (const float4*)(u + ig * 64);
        #pragma unroll
        for (int ii = 0; ii < 16; ++ii) {
            float4 uv = u4[ii];
            p = fmaf(uv.x, Ereg[4 * ii + 0], p);
            p = fmaf(uv.y, Ereg[4 * ii + 1], p);
            p = fmaf(uv.z, Ereg[4 * ii + 2], p);
            p = fmaf(uv.w, Ereg[4 * ii + 3], p);
        }
        if (ig == 1) part[j] = p;
        __syncthreads();
        float vnew = 0.f;
        if (ig == 0) vnew = (p + part[j]) * __expf(emv);
        float m = (ig == 0) ? vnew : 0.f;
        #pragma unroll
        for (int off = 32; off >= 1; off >>= 1) m = fmaxf(m, __shfl_xor(m, off));
        if (lane == 0) red[wid] = m;
        __syncthreads();
        float M = fmaxf(red[0], red[1]);
        if (ig == 0) u[j] = vnew / M;
        Cd += (double)__logf(M);
        __syncthreads();
        ++k;
    }

    // ---- z = C + log(sum_j u_j * exp(end_j)) ----
    float r = 0.f;
    if (ig == 0) r = u[j] * __expf(endt[j]);
    #pragma unroll
    for (int off = 32; off >= 1; off >>= 1) r += __shfl_xor(r, off);
    if (lane == 0) red[wid] = r;
    __syncthreads();
    if (t == 0) zout[b] = Cd + (double)__logf(red[0] + red[1]);
}

// ---- Kernel 3: posterior path score per batch ----
__global__ void post_kernel(const float* __restrict__ em, const void* __restrict__ maskp,
                            const int* __restrict__ tags, const void* __restrict__ forb,
                            const float* __restrict__ trans,
                            const float* __restrict__ startt, const float* __restrict__ endt,
                            double* __restrict__ postout)
{
    const int b = blockIdx.x;
    const int t = threadIdx.x;
    const int lane = t & 63;
    const int wid = t >> 6;
    const int mode = detect_mode(maskp);

    __shared__ int redi[4];
    __shared__ double redd[4];
    __shared__ int redc[4];

    int cnt = 0;
    for (int s = t; s < SS; s += BDIM) cnt += mask_at(maskp, mode, (size_t)b * SS + s);
    #pragma unroll
    for (int off = 32; off >= 1; off >>= 1) cnt += __shfl_xor(cnt, off);
    if (lane == 0) redi[wid] = cnt;
    __syncthreads();
    const int len = redi[0] + redi[1] + redi[2] + redi[3];

    const int* tg = tags + (size_t)b * SS;
    double local = 0.0;
    int fcnt = 0;
    for (int k = 1 + t; k < len; k += BDIM) {
        int tp = tg[k - 1], tc = tg[k];
        int fb = mask_at(forb, mode, (size_t)tp * TT + tc);
        if (fb) fcnt++; else local += (double)trans[tp * TT + tc];
        local += (double)em[((size_t)b * SS + k) * TT + tc];
    }
    if (t == 0) {
        local += (double)startt[tg[0]] + (double)em[(size_t)b * SS * TT + tg[0]];
        local += (double)endt[tg[len - 1]];
    }
    #pragma unroll
    for (int off = 32; off >= 1; off >>= 1) {
        local += __shfl_xor(local, off);
        fcnt  += __shfl_xor(fcnt, off);
    }
    if (lane == 0) { redd[wid] = local; redc[wid] = fcnt; }
    __syncthreads();
    if (t == 0) {
        double tot = redd[0] + redd[1] + redd[2] + redd[3];
        int fc = redc[0] + redc[1] + redc[2] + redc[3];
        postout[b] = tot - 100000.0 * (double)fc;  // exact integer count of IMPOSSIBLE terms
    }
}

// ---- Kernel 4: nll = mean(post) - mean(z) ----
__global__ void fin_kernel(const double* __restrict__ z, const double* __restrict__ post,
                           float* __restrict__ out) {
    int t = threadIdx.x; // 64 threads, 1 wave
    double pv = post[t];
    double zv = z[t];
    #pragma unroll
    for (int off = 32; off >= 1; off >>= 1) {
        pv += __shfl_xor(pv, off);
        zv += __shfl_xor(zv, off);
    }
    if (t == 0) out[0] = (float)((pv - zv) / (double)BB);
}

extern "C" void kernel_launch(void* const* d_in, const int* in_sizes, int n_in,
                              void* d_out, int out_size, void* d_ws, size_t ws_size,
                              hipStream_t stream) {
    const float* em     = (const float*)d_in[0];
    const void*  maskp  = d_in[1];
    const int*   tags   = (const int*)d_in[2];
    const void*  forb   = d_in[3];
    const float* trans  = (const float*)d_in[4];
    const float* startt = (const float*)d_in[5];
    const float* endt   = (const float*)d_in[6];

    float*  E    = (float*)d_ws;                          // 128*128 floats = 64 KB
    double* z    = (double*)((char*)d_ws + 65536);        // 64 doubles
    double* post = z + BB;                                // 64 doubles

    e_kernel  <<<(TT * TT + BDIM - 1) / BDIM, BDIM, 0, stream>>>(forb, trans, maskp, E);
    fwd_kernel<<<BB, BDIM, 0, stream>>>(em, maskp, startt, endt, E, z);
    post_kernel<<<BB, BDIM, 0, stream>>>(em, maskp, tags, forb, trans, startt, endt, post);
    fin_kernel<<<1, 64, 0, stream>>>(z, post, (float*)d_out);
}

// Round 2
// 1052.479 us; speedup vs baseline: 1.0275x; 1.0275x over previous
//
#include <hip/hip_runtime.h>
#include <hip/hip_bf16.h>
#include <stdint.h>

#define BB 64
#define SS 2048
#define TT 128
#define BDIM 256
#define G 8

// ---- bool-layout detection: mask[0,0] is always true (len >= 1024) ----
// mode 0: int32, 1: uint8, 2: float32, 3: bf16/u16
__device__ __forceinline__ int detect_mode(const void* maskp) {
    uint32_t w0 = ((const uint32_t*)maskp)[0];
    if (w0 == 1u) return 0;
    if (w0 == 0x3F800000u) return 2;
    if (w0 == 0x3F803F80u) return 3;
    return 1; // 0x01010101 (uint8) or anything else
}

__device__ __forceinline__ int mask_at(const void* maskp, int mode, size_t idx) {
    if (mode == 0) return ((const int*)maskp)[idx] != 0;
    if (mode == 1) return ((const unsigned char*)maskp)[idx] != 0;
    if (mode == 2) return ((const float*)maskp)[idx] != 0.f;
    return ((const unsigned short*)maskp)[idx] != 0;
}

// ---- Kernel 1: E[i][j] = forbidden ? 0 : exp(trans[i][j]) ----
__global__ void e_kernel(const void* __restrict__ forb, const float* __restrict__ trans,
                         const void* __restrict__ maskp, float* __restrict__ E) {
    int idx = blockIdx.x * BDIM + threadIdx.x;
    if (idx >= TT * TT) return;
    int mode = detect_mode(maskp);
    int fb = mask_at(forb, mode, idx);
    E[idx] = fb ? 0.0f : __expf(trans[idx]);
}

// ---- Kernel 2: forward scan (z) + posterior path score, one block per batch ----
__global__ __launch_bounds__(BDIM, 1) void fwd_kernel(
    const float* __restrict__ em, const void* __restrict__ maskp,
    const int* __restrict__ tags, const void* __restrict__ forb,
    const float* __restrict__ trans,
    const float* __restrict__ startt, const float* __restrict__ endt,
    const float* __restrict__ E, double* __restrict__ zout,
    double* __restrict__ postout)
{
    const int b = blockIdx.x;
    const int t = threadIdx.x;
    const int j = t >> 1;        // tag column this thread owns (0..127)
    const int h = t & 1;         // which i-half (0: i=0..63, 1: i=64..127)
    const int lane = t & 63;
    const int wid = t >> 6;

    __shared__ __align__(16) float u[2][TT];   // double-buffered exp-domain alpha
    __shared__ __align__(16) float red[4];
    __shared__ int redi[4];
    __shared__ double redd[4];
    __shared__ int redc[4];

    const int mode = detect_mode(maskp);

    // ---- length of this batch (mask is a contiguous prefix) ----
    int cnt = 0;
    for (int s = t; s < SS; s += BDIM) cnt += mask_at(maskp, mode, (size_t)b * SS + s);
    #pragma unroll
    for (int off = 32; off >= 1; off >>= 1) cnt += __shfl_xor(cnt, off);
    if (lane == 0) redi[wid] = cnt;
    __syncthreads();
    const int len = redi[0] + redi[1] + redi[2] + redi[3];

    // ---- this thread's 64-entry slice of E: E[h*64+i][j] ----
    float Ereg[64];
    {
        const float* Eb = E + (size_t)(h * 64) * TT + j;
        #pragma unroll
        for (int i = 0; i < 64; ++i) Ereg[i] = Eb[(size_t)i * TT];
    }

    const float* emB = em + (size_t)b * SS * TT;
    double Cd;
    float pending = 1.0f;   // deferred 1/M from the previous renorm step
    int cur = 0;

    // ---- init: alpha0 = start + em[:,0,:] -> exp domain ----
    {
        float a0 = startt[j] + emB[j];
        float m = a0;
        #pragma unroll
        for (int off = 32; off >= 1; off >>= 1) m = fmaxf(m, __shfl_xor(m, off));
        if (lane == 0) red[wid] = m;
        __syncthreads();
        float4 r4 = *(const float4*)red;
        float M = fmaxf(fmaxf(r4.x, r4.y), fmaxf(r4.z, r4.w));
        if (h == 0) u[0][j] = __expf(a0 - M);
        Cd = (double)M;
        __syncthreads();
    }

    // ---- main scan: groups of G steps, renorm on the last step of each group ----
    int k = 1;
    float emc[G], emn[G];
    #pragma unroll
    for (int g = 0; g < G; ++g) {
        int kk = k + g; kk = kk < SS ? kk : SS - 1;
        emc[g] = emB[(size_t)kk * TT + j];
    }

    while (k + G <= len) {
        // prefetch next group's emissions (in flight across this group's compute)
        #pragma unroll
        for (int g = 0; g < G; ++g) {
            int kk = k + G + g; kk = kk < SS ? kk : SS - 1;
            emn[g] = emB[(size_t)kk * TT + j];
        }
        #pragma unroll
        for (int g = 0; g < G; ++g) {
            // p = sum over this thread's i-half of u[i]*E[i][j]
            const float4* u4 = (const float4*)(&u[cur][h * 64]);
            float p0 = 0.f, p1 = 0.f, p2 = 0.f, p3 = 0.f;
            #pragma unroll
            for (int ii = 0; ii < 16; ++ii) {
                float4 uv = u4[ii];
                p0 = fmaf(uv.x, Ereg[4 * ii + 0], p0);
                p1 = fmaf(uv.y, Ereg[4 * ii + 1], p1);
                p2 = fmaf(uv.z, Ereg[4 * ii + 2], p2);
                p3 = fmaf(uv.w, Ereg[4 * ii + 3], p3);
            }
            float p = (p0 + p1) + (p2 + p3);
            p += __shfl_xor(p, 1);            // combine i-halves (same quad, cheap DPP)
            float v = (p * pending) * __expf(emc[g]);
            if (h == 0) u[cur ^ 1][j] = v;    // raw (unnormalized) write
            if (g == G - 1) {
                // renorm: block-max of v shares the step's single barrier
                float m = (h == 0) ? v : 0.f;
                #pragma unroll
                for (int off = 32; off >= 1; off >>= 1) m = fmaxf(m, __shfl_xor(m, off));
                if (lane == 0) red[wid] = m;
                __syncthreads();
                float4 r4 = *(const float4*)red;
                float M = fmaxf(fmaxf(r4.x, r4.y), fmaxf(r4.z, r4.w));
                pending = 1.0f / M;
                Cd += (double)__logf(M);
            } else {
                pending = 1.0f;
                __syncthreads();
            }
            cur ^= 1;
        }
        #pragma unroll
        for (int g = 0; g < G; ++g) emc[g] = emn[g];
        k += G;
    }

    // ---- tail steps (<G), renorm every step ----
    while (k < len) {
        float emv = emB[(size_t)k * TT + j];
        const float4* u4 = (const float4*)(&u[cur][h * 64]);
        float p0 = 0.f, p1 = 0.f, p2 = 0.f, p3 = 0.f;
        #pragma unroll
        for (int ii = 0; ii < 16; ++ii) {
            float4 uv = u4[ii];
            p0 = fmaf(uv.x, Ereg[4 * ii + 0], p0);
            p1 = fmaf(uv.y, Ereg[4 * ii + 1], p1);
            p2 = fmaf(uv.z, Ereg[4 * ii + 2], p2);
            p3 = fmaf(uv.w, Ereg[4 * ii + 3], p3);
        }
        float p = (p0 + p1) + (p2 + p3);
        p += __shfl_xor(p, 1);
        float v = (p * pending) * __expf(emv);
        if (h == 0) u[cur ^ 1][j] = v;
        float m = (h == 0) ? v : 0.f;
        #pragma unroll
        for (int off = 32; off >= 1; off >>= 1) m = fmaxf(m, __shfl_xor(m, off));
        if (lane == 0) red[wid] = m;
        __syncthreads();
        float4 r4 = *(const float4*)red;
        float M = fmaxf(fmaxf(r4.x, r4.y), fmaxf(r4.z, r4.w));
        pending = 1.0f / M;
        Cd += (double)__logf(M);
        cur ^= 1;
        ++k;
    }

    // ---- z = C + log(sum_j (u_j*pending) * exp(end_j)) ----
    {
        float r = 0.f;
        if (h == 0) r = (u[cur][j] * pending) * __expf(endt[j]);
        #pragma unroll
        for (int off = 32; off >= 1; off >>= 1) r += __shfl_xor(r, off);
        if (lane == 0) red[wid] = r;
        __syncthreads();
        float4 r4 = *(const float4*)red;
        float rt = (r4.x + r4.y) + (r4.z + r4.w);
        if (t == 0) zout[b] = Cd + (double)__logf(rt);
        __syncthreads();
    }

    // ---- phase 2: posterior path score for this batch ----
    {
        const int* tg = tags + (size_t)b * SS;
        double local = 0.0;
        int fcnt = 0;
        for (int kk = 1 + t; kk < len; kk += BDIM) {
            int tp = tg[kk - 1], tc = tg[kk];
            int fb = mask_at(forb, mode, (size_t)tp * TT + tc);
            if (fb) fcnt++; else local += (double)trans[tp * TT + tc];
            local += (double)em[((size_t)b * SS + kk) * TT + tc];
        }
        if (t == 0) {
            local += (double)startt[tg[0]] + (double)em[(size_t)b * SS * TT + tg[0]];
            local += (double)endt[tg[len - 1]];
        }
        #pragma unroll
        for (int off = 32; off >= 1; off >>= 1) {
            local += __shfl_xor(local, off);
            fcnt  += __shfl_xor(fcnt, off);
        }
        if (lane == 0) { redd[wid] = local; redc[wid] = fcnt; }
        __syncthreads();
        if (t == 0) {
            double tot = redd[0] + redd[1] + redd[2] + redd[3];
            int fc = redc[0] + redc[1] + redc[2] + redc[3];
            postout[b] = tot - 100000.0 * (double)fc;
        }
    }
}

// ---- Kernel 3: nll = mean(post) - mean(z) ----
__global__ void fin_kernel(const double* __restrict__ z, const double* __restrict__ post,
                           float* __restrict__ out) {
    int t = threadIdx.x; // 64 threads, 1 wave
    double pv = post[t];
    double zv = z[t];
    #pragma unroll
    for (int off = 32; off >= 1; off >>= 1) {
        pv += __shfl_xor(pv, off);
        zv += __shfl_xor(zv, off);
    }
    if (t == 0) out[0] = (float)((pv - zv) / (double)BB);
}

extern "C" void kernel_launch(void* const* d_in, const int* in_sizes, int n_in,
                              void* d_out, int out_size, void* d_ws, size_t ws_size,
                              hipStream_t stream) {
    const float* em     = (const float*)d_in[0];
    const void*  maskp  = d_in[1];
    const int*   tags   = (const int*)d_in[2];
    const void*  forb   = d_in[3];
    const float* trans  = (const float*)d_in[4];
    const float* startt = (const float*)d_in[5];
    const float* endt   = (const float*)d_in[6];

    float*  E    = (float*)d_ws;                          // 128*128 floats = 64 KB
    double* z    = (double*)((char*)d_ws + 65536);        // 64 doubles
    double* post = z + BB;                                // 64 doubles

    e_kernel  <<<(TT * TT + BDIM - 1) / BDIM, BDIM, 0, stream>>>(forb, trans, maskp, E);
    fwd_kernel<<<BB, BDIM, 0, stream>>>(em, maskp, tags, forb, trans, startt, endt, E, z, post);
    fin_kernel<<<1, 64, 0, stream>>>(z, post, (float*)d_out);
}